// Round 8
// baseline (427.425 us; speedup 1.0000x reference)
//
#include <hip/hip_runtime.h>
#include <stdint.h>

#define N_NODES 40000
#define N_EDGES 1280000
#define NODE_BLOCKS 313   // ceil(40000/128)

typedef __attribute__((ext_vector_type(8))) short bf16x8;   // 8 bf16 in 4 VGPRs
typedef __attribute__((ext_vector_type(4))) float f32x4;    // MFMA C/D

#define MFMA16(a, b, c) __builtin_amdgcn_mfma_f32_16x16x32_bf16((a), (b), (c), 0, 0, 0)

#if defined(__has_builtin)
#if __has_builtin(__builtin_amdgcn_cvt_pk_bf16_f32)
#define HAS_CVT_PK_BF16 1
#endif
#endif

// ---------- helpers ----------
__device__ __forceinline__ float fast_silu(float x) {
    float e = __expf(-x);
    return x * __builtin_amdgcn_rcpf(1.0f + e);
}

__device__ __forceinline__ unsigned short f2bf(float x) {
    unsigned int u = __float_as_uint(x);
    u = (u + 0x7FFFu + ((u >> 16) & 1u)) >> 16;
    return (unsigned short)u;
}

__device__ __forceinline__ unsigned int pack_bf2(float a, float b) {
#ifdef HAS_CVT_PK_BF16
    typedef __attribute__((ext_vector_type(2))) __bf16 bf2_t;
    bf2_t r = __builtin_amdgcn_cvt_pk_bf16_f32(a, b);   // low = a, high = b, RNE
    return __builtin_bit_cast(unsigned int, r);
#else
    unsigned int ua = __float_as_uint(a);
    unsigned int ub = __float_as_uint(b);
    ua = (ua + 0x7FFFu + ((ua >> 16) & 1u)) >> 16;
    ub = (ub + 0x7FFFu + ((ub >> 16) & 1u)) & 0xFFFF0000u;
    return (ua & 0xFFFFu) | ub;
#endif
}

__device__ __forceinline__ float bf16_to_f(unsigned short s) {
    return __uint_as_float(((unsigned int)s) << 16);
}

// ============================================================================
// prep + zero + hist fused (disjoint block ranges; hist zeroed by tiny memset
// BEFORE this kernel; agg/aggc zeroing here is safe — first read is 3
// dispatches later in the edge kernel).
//   [0, ZB)            : zero agg+aggc (40000*67 floats)
//   [ZB, ZB+2500)      : pack h -> bf16
//   [ZB+2500, ZB+2612) : pack weights (transpose)
//   [ZB+2612, ZB+3862) : histogram rows
// ============================================================================
#define ZB 2618   // ceil(40000*67/4 / 256)
__global__ void prep_hist_kernel(const float* __restrict__ h,
                                 const float* __restrict__ We1, const float* __restrict__ We2,
                                 const float* __restrict__ Wc1, const float* __restrict__ Wn1,
                                 const float* __restrict__ Wn2,
                                 const int* __restrict__ eidx,
                                 float* __restrict__ aggz,
                                 unsigned short* __restrict__ h_bf,
                                 unsigned short* __restrict__ Wt1, unsigned short* __restrict__ Wt2,
                                 unsigned short* __restrict__ Wtc1, unsigned short* __restrict__ Wtn1,
                                 unsigned short* __restrict__ Wtn2,
                                 int* __restrict__ hist)
{
    const int b = blockIdx.x;
    if (b < ZB) {
        const int i = (b * 256 + threadIdx.x) * 4;
        if (i < N_NODES * 67)
            *(float4*)(aggz + i) = make_float4(0.f, 0.f, 0.f, 0.f);
    } else if (b < ZB + 2500) {
        const int i = ((b - ZB) * 256 + threadIdx.x) * 4;   // exactly covers 2,560,000
        const float4 v = *(const float4*)(h + i);
        *(uint2*)(h_bf + i) = make_uint2(pack_bf2(v.x, v.y), pack_bf2(v.z, v.w));
    } else if (b < ZB + 2612) {
        const int t = (b - ZB - 2500) * 256 + threadIdx.x;
        if (t < 8192)       { Wt1[t]  = f2bf(We1[(t & 127) * 64 + (t >> 7)]); }
        else if (t < 12288) { int u = t - 8192;  Wt2[u]  = f2bf(We2[(u & 63) * 64 + (u >> 6)]); }
        else if (t < 16384) { int u = t - 12288; Wtc1[u] = f2bf(Wc1[(u & 63) * 64 + (u >> 6)]); }
        else if (t < 24576) { int u = t - 16384; Wtn1[u] = f2bf(Wn1[(u & 127) * 64 + (u >> 7)]); }
        else if (t < 28672) { int u = t - 24576; Wtn2[u] = f2bf(Wn2[(u & 63) * 64 + (u >> 6)]); }
    } else {
        const int i = ((b - ZB - 2612) * 256 + threadIdx.x) * 4;   // 1250 blocks, exact
        const int4 r = *(const int4*)(eidx + i);
        atomicAdd(&hist[r.x], 1);
        atomicAdd(&hist[r.y], 1);
        atomicAdd(&hist[r.z], 1);
        atomicAdd(&hist[r.w], 1);
    }
}

// ============================================================================
// single-block scan
// ============================================================================
__global__ __launch_bounds__(1024) void scan_kernel(const int* __restrict__ hist,
                                                    int* __restrict__ offs,
                                                    int* __restrict__ pos) {
    __shared__ int wtot[16];
    __shared__ int carry_s;
    const int t = threadIdx.x;
    const int wave = t >> 6, lane = t & 63;
    if (t == 0) carry_s = 0;
    __syncthreads();
    for (int base = 0; base < N_NODES; base += 8192) {
        const int idx = base + t * 8;
        int v[8];
        if (idx + 8 <= N_NODES) {
            const int4 a = *(const int4*)(hist + idx);
            const int4 b = *(const int4*)(hist + idx + 4);
            v[0] = a.x; v[1] = a.y; v[2] = a.z; v[3] = a.w;
            v[4] = b.x; v[5] = b.y; v[6] = b.z; v[7] = b.w;
        } else {
            #pragma unroll
            for (int j = 0; j < 8; ++j) v[j] = (idx + j < N_NODES) ? hist[idx + j] : 0;
        }
        int s = 0;
        #pragma unroll
        for (int j = 0; j < 8; ++j) s += v[j];
        int S = s;
        #pragma unroll
        for (int d = 1; d < 64; d <<= 1) {
            const int u = __shfl_up(S, d, 64);
            if (lane >= d) S += u;
        }
        if (lane == 63) wtot[wave] = S;
        __syncthreads();
        if (wave == 0 && lane < 16) {
            int w = wtot[lane];
            #pragma unroll
            for (int d = 1; d < 16; d <<= 1) {
                const int u = __shfl_up(w, d, 64);
                if (lane >= d) w += u;
            }
            wtot[lane] = w;
        }
        __syncthreads();
        const int wb = (wave == 0) ? 0 : wtot[wave - 1];
        int run = carry_s + wb + (S - s);
        #pragma unroll
        for (int j = 0; j < 8; ++j) {
            if (idx + j < N_NODES) { offs[idx + j] = run; pos[idx + j] = run; }
            run += v[j];
        }
        __syncthreads();
        if (t == 0) carry_s += wtot[15];
        __syncthreads();
    }
}

// ============================================================================
// scatter: one 8 B payload {row|col<<16, mask} per CSR slot
// ============================================================================
__global__ void scatter_kernel(const int* __restrict__ eidx, const float* __restrict__ emask,
                               int* __restrict__ pos, uint2* __restrict__ payload) {
    const int i = (blockIdx.x * 256 + threadIdx.x) * 4;
    const int4 r = *(const int4*)(eidx + i);
    const int4 c = *(const int4*)(eidx + N_EDGES + i);
    const float4 mk = *(const float4*)(emask + i);
    const int s0 = atomicAdd(&pos[r.x], 1);
    payload[s0] = make_uint2((unsigned)r.x | ((unsigned)c.x << 16), __float_as_uint(mk.x));
    const int s1 = atomicAdd(&pos[r.y], 1);
    payload[s1] = make_uint2((unsigned)r.y | ((unsigned)c.y << 16), __float_as_uint(mk.y));
    const int s2 = atomicAdd(&pos[r.z], 1);
    payload[s2] = make_uint2((unsigned)r.z | ((unsigned)c.z << 16), __float_as_uint(mk.z));
    const int s3 = atomicAdd(&pos[r.w], 1);
    payload[s3] = make_uint2((unsigned)r.w | ((unsigned)c.w << 16), __float_as_uint(mk.w));
}

// ============================================================================
// edge kernel: CSR payload, transposed-MFMA, fused aggregation.
// LDS = A(36864) + dif(3072) + cval(1024) = 40960 B exactly -> 4 blocks/CU.
// ============================================================================
__global__ __launch_bounds__(256, 4) void egcl_edge_mfma(
    const unsigned short* __restrict__ h_bf, const float* __restrict__ coord,
    const uint2* __restrict__ payload,
    const int* __restrict__ offs_g, const int* __restrict__ hist_g,
    const float* __restrict__ We1, const float* __restrict__ be1,
    const float* __restrict__ be2, const float* __restrict__ bc1,
    const float* __restrict__ Wc2,
    const unsigned short* __restrict__ Wt1, const unsigned short* __restrict__ Wt2,
    const unsigned short* __restrict__ Wtc1,
    float* __restrict__ agg, float* __restrict__ aggc)
{
    __shared__ __align__(16) unsigned short A[256 * 72];
    __shared__ float dif_s[768];
    __shared__ float cval_s[256];

    const int t = threadIdx.x;
    const int w = t >> 6, L = t & 63;
    const int q = L >> 4, lc = L & 15;
    const int ebase = blockIdx.x * 256;
    const int rbase = w * 64;

    // ---- meta: one coalesced 8B payload read per slot; keep in registers ----
    int my_r, my_c;
    float my_rad, my_msk;
    {
        const uint2 pl = payload[ebase + t];
        my_r = (int)(pl.x & 0xFFFFu);
        my_c = (int)(pl.x >> 16);
        my_msk = __uint_as_float(pl.y);
        const float d0 = coord[my_r * 3 + 0] - coord[my_c * 3 + 0];
        const float d1 = coord[my_r * 3 + 1] - coord[my_c * 3 + 1];
        const float d2 = coord[my_r * 3 + 2] - coord[my_c * 3 + 2];
        dif_s[t * 3 + 0] = d0; dif_s[t * 3 + 1] = d1; dif_s[t * 3 + 2] = d2;
        my_rad = d0 * d0 + d1 * d1 + d2 * d2;
        if (t == 0)   *(int*)&A[64] = my_r;   // n0 in row-0 padding
        if (t == 255) *(int*)&A[66] = my_r;   // n1
    }

    // ---- stage h_bf[row] (k = 0..63), wave-private rows via shfl ----
    #pragma unroll
    for (int it = 0; it < 8; ++it) {
        const int rloc = it * 8 + (L >> 3);
        const int part = L & 7;
        const int ridx = __shfl(my_r, rloc, 64);
        const bf16x8 v = *(const bf16x8*)(h_bf + (size_t)ridx * 64 + part * 8);
        *(bf16x8*)&A[(rbase + rloc) * 72 + part * 8] = v;
    }

    // per-et rad / mask via shfl (slot et*16+lc is in this wave)
    float rad_et[4], mk_et[4];
    #pragma unroll
    for (int et = 0; et < 4; ++et) {
        rad_et[et] = __shfl(my_rad, et * 16 + lc, 64);
        mk_et[et]  = __shfl(my_msk, et * 16 + lc, 64);
    }

    // ---- layer1 init ----
    f32x4 acc[4][4];   // [ot][et]
    #pragma unroll
    for (int ot = 0; ot < 4; ++ot) {
        const float4 bv = *(const float4*)(be1 + ot * 16 + q * 4);
        const float4 wv = *(const float4*)(We1 + 128 * 64 + ot * 16 + q * 4);
        #pragma unroll
        for (int et = 0; et < 4; ++et) {
            const float rad = rad_et[et];
            acc[ot][et][0] = fmaf(rad, wv.x, bv.x);
            acc[ot][et][1] = fmaf(rad, wv.y, bv.y);
            acc[ot][et][2] = fmaf(rad, wv.z, bv.z);
            acc[ot][et][3] = fmaf(rad, wv.w, bv.w);
        }
    }

    // ---- layer1 MFMA, k = 0..63 (h[row]) ----
    #pragma unroll
    for (int ks = 0; ks < 2; ++ks) {
        bf16x8 bfr[4];
        #pragma unroll
        for (int et = 0; et < 4; ++et)
            bfr[et] = *(const bf16x8*)&A[(rbase + et * 16 + lc) * 72 + ks * 32 + q * 8];
        #pragma unroll
        for (int ot = 0; ot < 4; ++ot) {
            const bf16x8 af = *(const bf16x8*)&Wt1[(ot * 16 + lc) * 128 + ks * 32 + q * 8];
            #pragma unroll
            for (int et = 0; et < 4; ++et)
                acc[ot][et] = MFMA16(af, bfr[et], acc[ot][et]);
        }
    }

    // ---- restage h_bf[col] ----
    #pragma unroll
    for (int it = 0; it < 8; ++it) {
        const int rloc = it * 8 + (L >> 3);
        const int part = L & 7;
        const int cidx = __shfl(my_c, rloc, 64);
        const bf16x8 v = *(const bf16x8*)(h_bf + (size_t)cidx * 64 + part * 8);
        *(bf16x8*)&A[(rbase + rloc) * 72 + part * 8] = v;
    }

    // ---- layer1 MFMA, k = 64..127 (h[col]) ----
    #pragma unroll
    for (int ks = 0; ks < 2; ++ks) {
        bf16x8 bfr[4];
        #pragma unroll
        for (int et = 0; et < 4; ++et)
            bfr[et] = *(const bf16x8*)&A[(rbase + et * 16 + lc) * 72 + ks * 32 + q * 8];
        #pragma unroll
        for (int ot = 0; ot < 4; ++ot) {
            const bf16x8 af = *(const bf16x8*)&Wt1[(ot * 16 + lc) * 128 + 64 + ks * 32 + q * 8];
            #pragma unroll
            for (int et = 0; et < 4; ++et)
                acc[ot][et] = MFMA16(af, bfr[et], acc[ot][et]);
        }
    }

    // ---- m1 = silu -> A (packed cvt) ----
    #pragma unroll
    for (int et = 0; et < 4; ++et) {
        const int row = rbase + et * 16 + lc;
        #pragma unroll
        for (int ot = 0; ot < 4; ++ot) {
            uint2 p;
            p.x = pack_bf2(fast_silu(acc[ot][et][0]), fast_silu(acc[ot][et][1]));
            p.y = pack_bf2(fast_silu(acc[ot][et][2]), fast_silu(acc[ot][et][3]));
            *(uint2*)&A[row * 72 + ot * 16 + q * 4] = p;
        }
    }

    // ---- layer2 ----
    f32x4 acc2[4][4];
    #pragma unroll
    for (int ot = 0; ot < 4; ++ot) {
        const float4 bv = *(const float4*)(be2 + ot * 16 + q * 4);
        #pragma unroll
        for (int et = 0; et < 4; ++et) {
            acc2[ot][et][0] = bv.x; acc2[ot][et][1] = bv.y;
            acc2[ot][et][2] = bv.z; acc2[ot][et][3] = bv.w;
        }
    }
    #pragma unroll
    for (int ks = 0; ks < 2; ++ks) {
        bf16x8 bfr[4];
        #pragma unroll
        for (int et = 0; et < 4; ++et)
            bfr[et] = *(const bf16x8*)&A[(rbase + et * 16 + lc) * 72 + ks * 32 + q * 8];
        #pragma unroll
        for (int ot = 0; ot < 4; ++ot) {
            const bf16x8 af = *(const bf16x8*)&Wt2[(ot * 16 + lc) * 64 + ks * 32 + q * 8];
            #pragma unroll
            for (int et = 0; et < 4; ++et)
                acc2[ot][et] = MFMA16(af, bfr[et], acc2[ot][et]);
        }
    }

    // ---- m = silu * mask -> A ----
    #pragma unroll
    for (int et = 0; et < 4; ++et) {
        const int row = rbase + et * 16 + lc;
        const float mk = mk_et[et];
        #pragma unroll
        for (int ot = 0; ot < 4; ++ot) {
            uint2 p;
            p.x = pack_bf2(fast_silu(acc2[ot][et][0]) * mk, fast_silu(acc2[ot][et][1]) * mk);
            p.y = pack_bf2(fast_silu(acc2[ot][et][2]) * mk, fast_silu(acc2[ot][et][3]) * mk);
            *(uint2*)&A[row * 72 + ot * 16 + q * 4] = p;
        }
    }

    // ---- coord mlp ----
    f32x4 acc3[4][4];
    #pragma unroll
    for (int ot = 0; ot < 4; ++ot) {
        const float4 bv = *(const float4*)(bc1 + ot * 16 + q * 4);
        #pragma unroll
        for (int et = 0; et < 4; ++et) {
            acc3[ot][et][0] = bv.x; acc3[ot][et][1] = bv.y;
            acc3[ot][et][2] = bv.z; acc3[ot][et][3] = bv.w;
        }
    }
    #pragma unroll
    for (int ks = 0; ks < 2; ++ks) {
        bf16x8 bfr[4];
        #pragma unroll
        for (int et = 0; et < 4; ++et)
            bfr[et] = *(const bf16x8*)&A[(rbase + et * 16 + lc) * 72 + ks * 32 + q * 8];
        #pragma unroll
        for (int ot = 0; ot < 4; ++ot) {
            const bf16x8 af = *(const bf16x8*)&Wtc1[(ot * 16 + lc) * 64 + ks * 32 + q * 8];
            #pragma unroll
            for (int et = 0; et < 4; ++et)
                acc3[ot][et] = MFMA16(af, bfr[et], acc3[ot][et]);
        }
    }
    {
        float4 wv[4];
        #pragma unroll
        for (int ot = 0; ot < 4; ++ot) wv[ot] = *(const float4*)(Wc2 + ot * 16 + q * 4);
        #pragma unroll
        for (int et = 0; et < 4; ++et) {
            float s = 0.0f;
            #pragma unroll
            for (int ot = 0; ot < 4; ++ot) {
                s = fmaf(fast_silu(acc3[ot][et][0]), wv[ot].x, s);
                s = fmaf(fast_silu(acc3[ot][et][1]), wv[ot].y, s);
                s = fmaf(fast_silu(acc3[ot][et][2]), wv[ot].z, s);
                s = fmaf(fast_silu(acc3[ot][et][3]), wv[ot].w, s);
            }
            s += __shfl_xor(s, 16, 64);
            s += __shfl_xor(s, 32, 64);
            if (q == 0)
                cval_s[rbase + et * 16 + lc] = s * mk_et[et];
        }
    }

    __syncthreads();   // whole block's m / cval / dif now valid

    // ---- fused segmented aggregation: 32 lanes x 2 channels, 2 slots/iter ----
    {
        const int n0 = *(const int*)&A[64];
        const int n1 = *(const int*)&A[66];
        const int half = L >> 5;          // lane half handles slots s0+half, +2...
        const int ch2 = (L & 31) * 2;     // channel pair
        for (int n = n0 + w; n <= n1; n += 4) {
            const int os = offs_g[n];
            const int dg = hist_g[n];
            const int s0 = max(os - ebase, 0);
            const int s1 = min(os + dg - ebase, 256);
            float slo = 0.0f, shi = 0.0f, t3 = 0.0f;
            const bool c3 = (L < 3);
            for (int slot = s0 + half; slot < s1; slot += 2) {
                const unsigned u = *(const unsigned*)&A[slot * 72 + ch2];
                slo += __uint_as_float(u << 16);
                shi += __uint_as_float(u & 0xFFFF0000u);
            }
            if (c3) {
                for (int slot = s0; slot < s1; ++slot)
                    t3 = fmaf(dif_s[slot * 3 + L], cval_s[slot], t3);
            }
            slo += __shfl_xor(slo, 32, 64);
            shi += __shfl_xor(shi, 32, 64);
            const bool interior = (os >= ebase) && (os + dg <= ebase + 256);
            if (L < 32) {
                if (interior) {
                    *(float2*)(agg + (size_t)n * 64 + ch2) = make_float2(slo, shi);
                } else {
                    atomicAdd(&agg[(size_t)n * 64 + ch2 + 0], slo);
                    atomicAdd(&agg[(size_t)n * 64 + ch2 + 1], shi);
                }
            }
            if (c3) {
                if (interior) aggc[n * 3 + L] = t3;
                else atomicAdd(&aggc[n * 3 + L], t3);
            }
        }
    }
}

// ============================================================================
// node MLP + coord output fused (block-uniform branch); reads pre-packed h_bf
// ============================================================================
__global__ __launch_bounds__(256, 4) void egcl_node_coord(
    const unsigned short* __restrict__ h_bf, const float* __restrict__ agg,
    const float* __restrict__ bn1, const float* __restrict__ bn2,
    const unsigned short* __restrict__ Wtn1, const unsigned short* __restrict__ Wtn2,
    const float* __restrict__ coord, const float* __restrict__ aggc,
    const int* __restrict__ hist,
    float* __restrict__ hout, float* __restrict__ cout)
{
    if (blockIdx.x >= NODE_BLOCKS) {
        const int i = (blockIdx.x - NODE_BLOCKS) * 256 + threadIdx.x;
        if (i < N_NODES * 3) {
            const int node = i / 3;
            const float c = fmaxf((float)hist[node], 1.0f);
            cout[i] = coord[i] + aggc[i] * __builtin_amdgcn_rcpf(c);
        }
        return;
    }

    __shared__ __align__(16) unsigned short A[128 * 136];
    const int t = threadIdx.x;
    const int wave = t >> 6, L = t & 63;
    const int q = L >> 4, lc = L & 15;
    const int nbase = blockIdx.x * 128;
    const int rbase = wave * 32;

    #pragma unroll 4
    for (int it = 0; it < 16; ++it) {
        const int idx = it * 256 + t;
        const int ln = idx >> 5, part = idx & 31;
        const int node = nbase + ln;
        uint2 u = make_uint2(0u, 0u);
        if (node < N_NODES) {
            if (part < 16) {
                u = *(const uint2*)(h_bf + (size_t)node * 64 + part * 4);
            } else {
                const float4 v = *(const float4*)(agg + (size_t)node * 64 + (part - 16) * 4);
                u = make_uint2(pack_bf2(v.x, v.y), pack_bf2(v.z, v.w));
            }
        }
        *(uint2*)&A[ln * 136 + part * 4] = u;
    }
    __syncthreads();

    f32x4 acc1[2][4];
    #pragma unroll
    for (int ct = 0; ct < 4; ++ct) {
        const float b = bn1[ct * 16 + lc];
        #pragma unroll
        for (int rt = 0; rt < 2; ++rt)
            #pragma unroll
            for (int i = 0; i < 4; ++i) acc1[rt][ct][i] = b;
    }
    #pragma unroll
    for (int ks = 0; ks < 4; ++ks) {
        bf16x8 af[2];
        #pragma unroll
        for (int rt = 0; rt < 2; ++rt)
            af[rt] = *(const bf16x8*)&A[(rbase + rt * 16 + lc) * 136 + ks * 32 + q * 8];
        #pragma unroll
        for (int ct = 0; ct < 4; ++ct) {
            const bf16x8 bf = *(const bf16x8*)&Wtn1[(ct * 16 + lc) * 128 + ks * 32 + q * 8];
            #pragma unroll
            for (int rt = 0; rt < 2; ++rt)
                acc1[rt][ct] = MFMA16(af[rt], bf, acc1[rt][ct]);
        }
    }
    __syncthreads();

    #pragma unroll
    for (int rt = 0; rt < 2; ++rt)
        #pragma unroll
        for (int ct = 0; ct < 4; ++ct)
            #pragma unroll
            for (int i = 0; i < 4; ++i) {
                const int row = rbase + rt * 16 + q * 4 + i;
                A[row * 72 + ct * 16 + lc] = f2bf(fast_silu(acc1[rt][ct][i]));
            }
    __syncthreads();

    f32x4 acc2[2][4];
    #pragma unroll
    for (int ct = 0; ct < 4; ++ct) {
        const float b = bn2[ct * 16 + lc];
        #pragma unroll
        for (int rt = 0; rt < 2; ++rt)
            #pragma unroll
            for (int i = 0; i < 4; ++i) acc2[rt][ct][i] = b;
    }
    #pragma unroll
    for (int ks = 0; ks < 2; ++ks) {
        bf16x8 af[2];
        #pragma unroll
        for (int rt = 0; rt < 2; ++rt)
            af[rt] = *(const bf16x8*)&A[(rbase + rt * 16 + lc) * 72 + ks * 32 + q * 8];
        #pragma unroll
        for (int ct = 0; ct < 4; ++ct) {
            const bf16x8 bf = *(const bf16x8*)&Wtn2[(ct * 16 + lc) * 64 + ks * 32 + q * 8];
            #pragma unroll
            for (int rt = 0; rt < 2; ++rt)
                acc2[rt][ct] = MFMA16(af[rt], bf, acc2[rt][ct]);
        }
    }

    #pragma unroll
    for (int rt = 0; rt < 2; ++rt)
        #pragma unroll
        for (int ct = 0; ct < 4; ++ct)
            #pragma unroll
            for (int i = 0; i < 4; ++i) {
                const int node = nbase + rbase + rt * 16 + q * 4 + i;
                if (node < N_NODES)
                    hout[(size_t)node * 64 + ct * 16 + lc] = acc2[rt][ct][i];
            }
}

// ============================================================================
// launch
// ============================================================================
extern "C" void kernel_launch(void* const* d_in, const int* in_sizes, int n_in,
                              void* d_out, int out_size, void* d_ws, size_t ws_size,
                              hipStream_t stream)
{
    const float* h     = (const float*)d_in[0];
    const float* coord = (const float*)d_in[1];
    const int*   eidx  = (const int*)d_in[2];
    const float* emask = (const float*)d_in[3];
    const float* We1   = (const float*)d_in[4];
    const float* be1   = (const float*)d_in[5];
    const float* We2   = (const float*)d_in[6];
    const float* be2   = (const float*)d_in[7];
    const float* Wn1   = (const float*)d_in[8];
    const float* bn1   = (const float*)d_in[9];
    const float* Wn2   = (const float*)d_in[10];
    const float* bn2   = (const float*)d_in[11];
    const float* Wc1   = (const float*)d_in[12];
    const float* bc1   = (const float*)d_in[13];
    const float* Wc2   = (const float*)d_in[14];

    float* hout = (float*)d_out;
    float* cout = hout + (size_t)N_NODES * 64;

    // ws layout: [agg | aggc] zeroed by prep; hist zeroed by tiny memset.
    char* p = (char*)d_ws;
    float* agg  = (float*)p;                      p += (size_t)N_NODES * 64 * 4; // 10.24 MB
    float* aggc = (float*)p;                      p += (size_t)N_NODES * 3 * 4;  // 0.48 MB
    int* hist   = (int*)p;                        p += (size_t)N_NODES * 4;      // 0.16 MB
    int* offs   = (int*)p;                        p += (size_t)N_NODES * 4;
    int* pos    = (int*)p;                        p += (size_t)N_NODES * 4;
    uint2* payload = (uint2*)p;                   p += (size_t)N_EDGES * 8;      // 10.24 MB
    unsigned short* h_bf = (unsigned short*)p;    p += (size_t)N_NODES * 64 * 2; // 5.12 MB
    unsigned short* Wt1  = (unsigned short*)p;    p += 8192 * 2;
    unsigned short* Wt2  = (unsigned short*)p;    p += 4096 * 2;
    unsigned short* Wtc1 = (unsigned short*)p;    p += 4096 * 2;
    unsigned short* Wtn1 = (unsigned short*)p;    p += 8192 * 2;
    unsigned short* Wtn2 = (unsigned short*)p;    p += 4096 * 2;

    hipMemsetAsync(hist, 0, (size_t)N_NODES * 4, stream);   // 160 KB only
    prep_hist_kernel<<<ZB + 3862, 256, 0, stream>>>(h, We1, We2, Wc1, Wn1, Wn2, eidx,
                                                    agg, h_bf, Wt1, Wt2, Wtc1, Wtn1, Wtn2, hist);
    scan_kernel<<<1, 1024, 0, stream>>>(hist, offs, pos);
    scatter_kernel<<<N_EDGES / 1024, 256, 0, stream>>>(eidx, emask, pos, payload);
    egcl_edge_mfma<<<N_EDGES / 256, 256, 0, stream>>>(
        h_bf, coord, payload, offs, hist,
        We1, be1, be2, bc1, Wc2, Wt1, Wt2, Wtc1, agg, aggc);
    egcl_node_coord<<<NODE_BLOCKS + (N_NODES * 3 + 255) / 256, 256, 0, stream>>>(
        h_bf, agg, bn1, bn2, Wtn1, Wtn2, coord, aggc, hist, hout, cout);
}

// Round 9
// 383.044 us; speedup vs baseline: 1.1159x; 1.1159x over previous
//
#include <hip/hip_runtime.h>
#include <stdint.h>

#define N_NODES 40000
#define N_EDGES 1280000
#define NODE_BLOCKS 313   // ceil(40000/128)

typedef __attribute__((ext_vector_type(8))) short bf16x8;   // 8 bf16 in 4 VGPRs
typedef __attribute__((ext_vector_type(4))) float f32x4;    // MFMA C/D
typedef __attribute__((ext_vector_type(2))) _Float16 f16x2;

#define MFMA16(a, b, c) __builtin_amdgcn_mfma_f32_16x16x32_bf16((a), (b), (c), 0, 0, 0)

#if defined(__has_builtin)
#if __has_builtin(__builtin_amdgcn_cvt_pk_bf16_f32)
#define HAS_CVT_PK_BF16 1
#endif
#endif

// ---------- helpers ----------
__device__ __forceinline__ float fast_silu(float x) {
    float e = __expf(-x);
    return x * __builtin_amdgcn_rcpf(1.0f + e);
}

__device__ __forceinline__ unsigned short f2bf(float x) {
    unsigned int u = __float_as_uint(x);
    u = (u + 0x7FFFu + ((u >> 16) & 1u)) >> 16;
    return (unsigned short)u;
}

__device__ __forceinline__ unsigned int pack_bf2(float a, float b) {
#ifdef HAS_CVT_PK_BF16
    typedef __attribute__((ext_vector_type(2))) __bf16 bf2_t;
    bf2_t r = __builtin_amdgcn_cvt_pk_bf16_f32(a, b);   // low = a, high = b, RNE
    return __builtin_bit_cast(unsigned int, r);
#else
    unsigned int ua = __float_as_uint(a);
    unsigned int ub = __float_as_uint(b);
    ua = (ua + 0x7FFFu + ((ua >> 16) & 1u)) >> 16;
    ub = (ub + 0x7FFFu + ((ub >> 16) & 1u)) & 0xFFFF0000u;
    return (ua & 0xFFFFu) | ub;
#endif
}

__device__ __forceinline__ float bf16_to_f(unsigned short s) {
    return __uint_as_float(((unsigned int)s) << 16);
}

__device__ __forceinline__ unsigned int pk_f16(float a, float b) {
    f16x2 v; v.x = (_Float16)a; v.y = (_Float16)b;
    return __builtin_bit_cast(unsigned int, v);
}
__device__ __forceinline__ float f16_lo(unsigned int u) {
    f16x2 v = __builtin_bit_cast(f16x2, u); return (float)v.x;
}
__device__ __forceinline__ float f16_hi(unsigned int u) {
    f16x2 v = __builtin_bit_cast(f16x2, u); return (float)v.y;
}

// ============================================================================
// prep + zero + hist fused (disjoint block ranges; hist zeroed by tiny memset
// BEFORE this kernel; agg/aggc zeroing here is safe — first read is 3
// dispatches later in the edge kernel).
//   [0, 2618)       : zero agg+aggc (40000*67 floats)
//   [2618, 5118)    : pack h -> bf16
//   [5118, 5230)    : pack weights (transpose)
//   [5230, 5387)    : pack coord -> float4
//   [5387, 6637)    : histogram rows
// ============================================================================
__global__ void prep_hist_kernel(const float* __restrict__ h, const float* __restrict__ coord,
                                 const float* __restrict__ We1, const float* __restrict__ We2,
                                 const float* __restrict__ Wc1, const float* __restrict__ Wn1,
                                 const float* __restrict__ Wn2,
                                 const int* __restrict__ eidx,
                                 float* __restrict__ aggz,
                                 unsigned short* __restrict__ h_bf,
                                 float4* __restrict__ coord4,
                                 unsigned short* __restrict__ Wt1, unsigned short* __restrict__ Wt2,
                                 unsigned short* __restrict__ Wtc1, unsigned short* __restrict__ Wtn1,
                                 unsigned short* __restrict__ Wtn2,
                                 int* __restrict__ hist)
{
    const int b = blockIdx.x;
    if (b < 2618) {
        const int i = (b * 256 + threadIdx.x) * 4;
        if (i < N_NODES * 67)
            *(float4*)(aggz + i) = make_float4(0.f, 0.f, 0.f, 0.f);
    } else if (b < 5118) {
        const int i = ((b - 2618) * 256 + threadIdx.x) * 4;   // exactly covers 2,560,000
        const float4 v = *(const float4*)(h + i);
        *(uint2*)(h_bf + i) = make_uint2(pack_bf2(v.x, v.y), pack_bf2(v.z, v.w));
    } else if (b < 5230) {
        const int t = (b - 5118) * 256 + threadIdx.x;
        if (t < 8192)       { Wt1[t]  = f2bf(We1[(t & 127) * 64 + (t >> 7)]); }
        else if (t < 12288) { int u = t - 8192;  Wt2[u]  = f2bf(We2[(u & 63) * 64 + (u >> 6)]); }
        else if (t < 16384) { int u = t - 12288; Wtc1[u] = f2bf(Wc1[(u & 63) * 64 + (u >> 6)]); }
        else if (t < 24576) { int u = t - 16384; Wtn1[u] = f2bf(Wn1[(u & 127) * 64 + (u >> 7)]); }
        else if (t < 28672) { int u = t - 24576; Wtn2[u] = f2bf(Wn2[(u & 63) * 64 + (u >> 6)]); }
    } else if (b < 5387) {
        const int n = (b - 5230) * 256 + threadIdx.x;
        if (n < N_NODES)
            coord4[n] = make_float4(coord[n * 3 + 0], coord[n * 3 + 1], coord[n * 3 + 2], 0.f);
    } else {
        const int i = ((b - 5387) * 256 + threadIdx.x) * 4;   // 1250 blocks, exact
        const int4 r = *(const int4*)(eidx + i);
        atomicAdd(&hist[r.x], 1);
        atomicAdd(&hist[r.y], 1);
        atomicAdd(&hist[r.z], 1);
        atomicAdd(&hist[r.w], 1);
    }
}

// ============================================================================
// single-block scan (proven)
// ============================================================================
__global__ __launch_bounds__(1024) void scan_kernel(const int* __restrict__ hist,
                                                    int* __restrict__ offs,
                                                    int* __restrict__ pos) {
    __shared__ int wtot[16];
    __shared__ int carry_s;
    const int t = threadIdx.x;
    const int wave = t >> 6, lane = t & 63;
    if (t == 0) carry_s = 0;
    __syncthreads();
    for (int base = 0; base < N_NODES; base += 8192) {
        const int idx = base + t * 8;
        int v[8];
        if (idx + 8 <= N_NODES) {
            const int4 a = *(const int4*)(hist + idx);
            const int4 b = *(const int4*)(hist + idx + 4);
            v[0] = a.x; v[1] = a.y; v[2] = a.z; v[3] = a.w;
            v[4] = b.x; v[5] = b.y; v[6] = b.z; v[7] = b.w;
        } else {
            #pragma unroll
            for (int j = 0; j < 8; ++j) v[j] = (idx + j < N_NODES) ? hist[idx + j] : 0;
        }
        int s = 0;
        #pragma unroll
        for (int j = 0; j < 8; ++j) s += v[j];
        int S = s;
        #pragma unroll
        for (int d = 1; d < 64; d <<= 1) {
            const int u = __shfl_up(S, d, 64);
            if (lane >= d) S += u;
        }
        if (lane == 63) wtot[wave] = S;
        __syncthreads();
        if (wave == 0 && lane < 16) {
            int w = wtot[lane];
            #pragma unroll
            for (int d = 1; d < 16; d <<= 1) {
                const int u = __shfl_up(w, d, 64);
                if (lane >= d) w += u;
            }
            wtot[lane] = w;
        }
        __syncthreads();
        const int wb = (wave == 0) ? 0 : wtot[wave - 1];
        int run = carry_s + wb + (S - s);
        #pragma unroll
        for (int j = 0; j < 8; ++j) {
            if (idx + j < N_NODES) { offs[idx + j] = run; pos[idx + j] = run; }
            run += v[j];
        }
        __syncthreads();
        if (t == 0) carry_s += wtot[15];
        __syncthreads();
    }
}

// ============================================================================
// scatter: one 16 B payload {r|c<<16, f16(d0,d1), f16(d2,mask), f32 rad}
// per CSR slot. Coord math done here (latency hides under the slot atomics).
// ============================================================================
__device__ __forceinline__ void scatter_one(int r, int c, float mk,
                                            const float4* __restrict__ coord4,
                                            int* __restrict__ pos,
                                            uint4* __restrict__ payload) {
    const float4 cr = coord4[r];
    const float4 cc = coord4[c];
    const float d0 = cr.x - cc.x, d1 = cr.y - cc.y, d2 = cr.z - cc.z;
    const float rad = d0 * d0 + d1 * d1 + d2 * d2;
    const int slot = atomicAdd(&pos[r], 1);
    payload[slot] = make_uint4((unsigned)r | ((unsigned)c << 16),
                               pk_f16(d0, d1), pk_f16(d2, mk),
                               __float_as_uint(rad));
}

__global__ void scatter_kernel(const int* __restrict__ eidx, const float* __restrict__ emask,
                               const float4* __restrict__ coord4,
                               int* __restrict__ pos, uint4* __restrict__ payload) {
    const int i = (blockIdx.x * 256 + threadIdx.x) * 4;
    const int4 r = *(const int4*)(eidx + i);
    const int4 c = *(const int4*)(eidx + N_EDGES + i);
    const float4 mk = *(const float4*)(emask + i);
    scatter_one(r.x, c.x, mk.x, coord4, pos, payload);
    scatter_one(r.y, c.y, mk.y, coord4, pos, payload);
    scatter_one(r.z, c.z, mk.z, coord4, pos, payload);
    scatter_one(r.w, c.w, mk.w, coord4, pos, payload);
}

// ============================================================================
// edge kernel: 16B CSR payload (no coord loads), transposed-MFMA, fused
// aggregation (R7-form loop). LDS = 40960 B exactly -> 4 blocks/CU.
// ============================================================================
__global__ __launch_bounds__(256, 4) void egcl_edge_mfma(
    const unsigned short* __restrict__ h_bf,
    const uint4* __restrict__ payload,
    const int* __restrict__ offs_g, const int* __restrict__ hist_g,
    const float* __restrict__ We1, const float* __restrict__ be1,
    const float* __restrict__ be2, const float* __restrict__ bc1,
    const float* __restrict__ Wc2,
    const unsigned short* __restrict__ Wt1, const unsigned short* __restrict__ Wt2,
    const unsigned short* __restrict__ Wtc1,
    float* __restrict__ agg, float* __restrict__ aggc)
{
    __shared__ __align__(16) unsigned short A[256 * 72];
    __shared__ float dif_s[768];
    __shared__ float cval_s[256];

    const int t = threadIdx.x;
    const int w = t >> 6, L = t & 63;
    const int q = L >> 4, lc = L & 15;
    const int ebase = blockIdx.x * 256;
    const int rbase = w * 64;

    // ---- meta: ONE coalesced 16B payload read; no dependent random loads ----
    int my_r, my_c;
    float my_rad, my_msk;
    {
        const uint4 pl = payload[ebase + t];
        my_r = (int)(pl.x & 0xFFFFu);
        my_c = (int)(pl.x >> 16);
        const float d0 = f16_lo(pl.y);
        const float d1 = f16_hi(pl.y);
        const float d2 = f16_lo(pl.z);
        my_msk = f16_hi(pl.z);
        my_rad = __uint_as_float(pl.w);
        dif_s[t * 3 + 0] = d0; dif_s[t * 3 + 1] = d1; dif_s[t * 3 + 2] = d2;
        if (t == 0)   *(int*)&A[64] = my_r;   // n0 in row-0 padding
        if (t == 255) *(int*)&A[66] = my_r;   // n1
    }

    // ---- stage h_bf[row] (k = 0..63), wave-private rows via shfl ----
    #pragma unroll
    for (int it = 0; it < 8; ++it) {
        const int rloc = it * 8 + (L >> 3);
        const int part = L & 7;
        const int ridx = __shfl(my_r, rloc, 64);
        const bf16x8 v = *(const bf16x8*)(h_bf + (size_t)ridx * 64 + part * 8);
        *(bf16x8*)&A[(rbase + rloc) * 72 + part * 8] = v;
    }

    // per-et rad / mask via shfl (slot et*16+lc is in this wave)
    float rad_et[4], mk_et[4];
    #pragma unroll
    for (int et = 0; et < 4; ++et) {
        rad_et[et] = __shfl(my_rad, et * 16 + lc, 64);
        mk_et[et]  = __shfl(my_msk, et * 16 + lc, 64);
    }

    // ---- layer1 init ----
    f32x4 acc[4][4];   // [ot][et]
    #pragma unroll
    for (int ot = 0; ot < 4; ++ot) {
        const float4 bv = *(const float4*)(be1 + ot * 16 + q * 4);
        const float4 wv = *(const float4*)(We1 + 128 * 64 + ot * 16 + q * 4);
        #pragma unroll
        for (int et = 0; et < 4; ++et) {
            const float rad = rad_et[et];
            acc[ot][et][0] = fmaf(rad, wv.x, bv.x);
            acc[ot][et][1] = fmaf(rad, wv.y, bv.y);
            acc[ot][et][2] = fmaf(rad, wv.z, bv.z);
            acc[ot][et][3] = fmaf(rad, wv.w, bv.w);
        }
    }

    // ---- layer1 MFMA, k = 0..63 (h[row]) ----
    #pragma unroll
    for (int ks = 0; ks < 2; ++ks) {
        bf16x8 bfr[4];
        #pragma unroll
        for (int et = 0; et < 4; ++et)
            bfr[et] = *(const bf16x8*)&A[(rbase + et * 16 + lc) * 72 + ks * 32 + q * 8];
        #pragma unroll
        for (int ot = 0; ot < 4; ++ot) {
            const bf16x8 af = *(const bf16x8*)&Wt1[(ot * 16 + lc) * 128 + ks * 32 + q * 8];
            #pragma unroll
            for (int et = 0; et < 4; ++et)
                acc[ot][et] = MFMA16(af, bfr[et], acc[ot][et]);
        }
    }

    // ---- restage h_bf[col] ----
    #pragma unroll
    for (int it = 0; it < 8; ++it) {
        const int rloc = it * 8 + (L >> 3);
        const int part = L & 7;
        const int cidx = __shfl(my_c, rloc, 64);
        const bf16x8 v = *(const bf16x8*)(h_bf + (size_t)cidx * 64 + part * 8);
        *(bf16x8*)&A[(rbase + rloc) * 72 + part * 8] = v;
    }

    // ---- layer1 MFMA, k = 64..127 (h[col]) ----
    #pragma unroll
    for (int ks = 0; ks < 2; ++ks) {
        bf16x8 bfr[4];
        #pragma unroll
        for (int et = 0; et < 4; ++et)
            bfr[et] = *(const bf16x8*)&A[(rbase + et * 16 + lc) * 72 + ks * 32 + q * 8];
        #pragma unroll
        for (int ot = 0; ot < 4; ++ot) {
            const bf16x8 af = *(const bf16x8*)&Wt1[(ot * 16 + lc) * 128 + 64 + ks * 32 + q * 8];
            #pragma unroll
            for (int et = 0; et < 4; ++et)
                acc[ot][et] = MFMA16(af, bfr[et], acc[ot][et]);
        }
    }

    // ---- m1 = silu -> A ----
    #pragma unroll
    for (int et = 0; et < 4; ++et) {
        const int row = rbase + et * 16 + lc;
        #pragma unroll
        for (int ot = 0; ot < 4; ++ot) {
            uint2 p;
            p.x = pack_bf2(fast_silu(acc[ot][et][0]), fast_silu(acc[ot][et][1]));
            p.y = pack_bf2(fast_silu(acc[ot][et][2]), fast_silu(acc[ot][et][3]));
            *(uint2*)&A[row * 72 + ot * 16 + q * 4] = p;
        }
    }

    // ---- layer2 ----
    f32x4 acc2[4][4];
    #pragma unroll
    for (int ot = 0; ot < 4; ++ot) {
        const float4 bv = *(const float4*)(be2 + ot * 16 + q * 4);
        #pragma unroll
        for (int et = 0; et < 4; ++et) {
            acc2[ot][et][0] = bv.x; acc2[ot][et][1] = bv.y;
            acc2[ot][et][2] = bv.z; acc2[ot][et][3] = bv.w;
        }
    }
    #pragma unroll
    for (int ks = 0; ks < 2; ++ks) {
        bf16x8 bfr[4];
        #pragma unroll
        for (int et = 0; et < 4; ++et)
            bfr[et] = *(const bf16x8*)&A[(rbase + et * 16 + lc) * 72 + ks * 32 + q * 8];
        #pragma unroll
        for (int ot = 0; ot < 4; ++ot) {
            const bf16x8 af = *(const bf16x8*)&Wt2[(ot * 16 + lc) * 64 + ks * 32 + q * 8];
            #pragma unroll
            for (int et = 0; et < 4; ++et)
                acc2[ot][et] = MFMA16(af, bfr[et], acc2[ot][et]);
        }
    }

    // ---- m = silu * mask -> A ----
    #pragma unroll
    for (int et = 0; et < 4; ++et) {
        const int row = rbase + et * 16 + lc;
        const float mk = mk_et[et];
        #pragma unroll
        for (int ot = 0; ot < 4; ++ot) {
            uint2 p;
            p.x = pack_bf2(fast_silu(acc2[ot][et][0]) * mk, fast_silu(acc2[ot][et][1]) * mk);
            p.y = pack_bf2(fast_silu(acc2[ot][et][2]) * mk, fast_silu(acc2[ot][et][3]) * mk);
            *(uint2*)&A[row * 72 + ot * 16 + q * 4] = p;
        }
    }

    // ---- coord mlp ----
    f32x4 acc3[4][4];
    #pragma unroll
    for (int ot = 0; ot < 4; ++ot) {
        const float4 bv = *(const float4*)(bc1 + ot * 16 + q * 4);
        #pragma unroll
        for (int et = 0; et < 4; ++et) {
            acc3[ot][et][0] = bv.x; acc3[ot][et][1] = bv.y;
            acc3[ot][et][2] = bv.z; acc3[ot][et][3] = bv.w;
        }
    }
    #pragma unroll
    for (int ks = 0; ks < 2; ++ks) {
        bf16x8 bfr[4];
        #pragma unroll
        for (int et = 0; et < 4; ++et)
            bfr[et] = *(const bf16x8*)&A[(rbase + et * 16 + lc) * 72 + ks * 32 + q * 8];
        #pragma unroll
        for (int ot = 0; ot < 4; ++ot) {
            const bf16x8 af = *(const bf16x8*)&Wtc1[(ot * 16 + lc) * 64 + ks * 32 + q * 8];
            #pragma unroll
            for (int et = 0; et < 4; ++et)
                acc3[ot][et] = MFMA16(af, bfr[et], acc3[ot][et]);
        }
    }
    {
        float4 wv[4];
        #pragma unroll
        for (int ot = 0; ot < 4; ++ot) wv[ot] = *(const float4*)(Wc2 + ot * 16 + q * 4);
        #pragma unroll
        for (int et = 0; et < 4; ++et) {
            float s = 0.0f;
            #pragma unroll
            for (int ot = 0; ot < 4; ++ot) {
                s = fmaf(fast_silu(acc3[ot][et][0]), wv[ot].x, s);
                s = fmaf(fast_silu(acc3[ot][et][1]), wv[ot].y, s);
                s = fmaf(fast_silu(acc3[ot][et][2]), wv[ot].z, s);
                s = fmaf(fast_silu(acc3[ot][et][3]), wv[ot].w, s);
            }
            s += __shfl_xor(s, 16, 64);
            s += __shfl_xor(s, 32, 64);
            if (q == 0)
                cval_s[rbase + et * 16 + lc] = s * mk_et[et];
        }
    }

    __syncthreads();   // whole block's m / cval / dif now valid

    // ---- fused segmented aggregation (R7-form per-lane loop) ----
    {
        const int n0 = *(const int*)&A[64];
        const int n1 = *(const int*)&A[66];
        for (int n = n0 + w; n <= n1; n += 4) {
            const int os = offs_g[n];
            const int dg = hist_g[n];
            const int s0 = max(os - ebase, 0);
            const int s1 = min(os + dg - ebase, 256);
            float s = 0.0f, t3 = 0.0f;
            const bool c3 = (L < 3);
            int slot = s0;
            for (; slot + 4 <= s1; slot += 4) {
                const float a0 = bf16_to_f(A[(slot + 0) * 72 + L]);
                const float a1 = bf16_to_f(A[(slot + 1) * 72 + L]);
                const float a2 = bf16_to_f(A[(slot + 2) * 72 + L]);
                const float a3 = bf16_to_f(A[(slot + 3) * 72 + L]);
                s += (a0 + a1) + (a2 + a3);
                if (c3) {
                    t3 = fmaf(dif_s[(slot + 0) * 3 + L], cval_s[slot + 0], t3);
                    t3 = fmaf(dif_s[(slot + 1) * 3 + L], cval_s[slot + 1], t3);
                    t3 = fmaf(dif_s[(slot + 2) * 3 + L], cval_s[slot + 2], t3);
                    t3 = fmaf(dif_s[(slot + 3) * 3 + L], cval_s[slot + 3], t3);
                }
            }
            for (; slot < s1; ++slot) {
                s += bf16_to_f(A[slot * 72 + L]);
                if (c3) t3 = fmaf(dif_s[slot * 3 + L], cval_s[slot], t3);
            }
            const bool interior = (os >= ebase) && (os + dg <= ebase + 256);
            if (interior) {
                agg[(size_t)n * 64 + L] = s;
                if (c3) aggc[n * 3 + L] = t3;
            } else {
                atomicAdd(&agg[(size_t)n * 64 + L], s);
                if (c3) atomicAdd(&aggc[n * 3 + L], t3);
            }
        }
    }
}

// ============================================================================
// node MLP + coord output fused (block-uniform branch); reads pre-packed h_bf
// ============================================================================
__global__ __launch_bounds__(256, 4) void egcl_node_coord(
    const unsigned short* __restrict__ h_bf, const float* __restrict__ agg,
    const float* __restrict__ bn1, const float* __restrict__ bn2,
    const unsigned short* __restrict__ Wtn1, const unsigned short* __restrict__ Wtn2,
    const float* __restrict__ coord, const float* __restrict__ aggc,
    const int* __restrict__ hist,
    float* __restrict__ hout, float* __restrict__ cout)
{
    if (blockIdx.x >= NODE_BLOCKS) {
        const int i = (blockIdx.x - NODE_BLOCKS) * 256 + threadIdx.x;
        if (i < N_NODES * 3) {
            const int node = i / 3;
            const float c = fmaxf((float)hist[node], 1.0f);
            cout[i] = coord[i] + aggc[i] * __builtin_amdgcn_rcpf(c);
        }
        return;
    }

    __shared__ __align__(16) unsigned short A[128 * 136];
    const int t = threadIdx.x;
    const int wave = t >> 6, L = t & 63;
    const int q = L >> 4, lc = L & 15;
    const int nbase = blockIdx.x * 128;
    const int rbase = wave * 32;

    #pragma unroll 4
    for (int it = 0; it < 16; ++it) {
        const int idx = it * 256 + t;
        const int ln = idx >> 5, part = idx & 31;
        const int node = nbase + ln;
        uint2 u = make_uint2(0u, 0u);
        if (node < N_NODES) {
            if (part < 16) {
                u = *(const uint2*)(h_bf + (size_t)node * 64 + part * 4);
            } else {
                const float4 v = *(const float4*)(agg + (size_t)node * 64 + (part - 16) * 4);
                u = make_uint2(pack_bf2(v.x, v.y), pack_bf2(v.z, v.w));
            }
        }
        *(uint2*)&A[ln * 136 + part * 4] = u;
    }
    __syncthreads();

    f32x4 acc1[2][4];
    #pragma unroll
    for (int ct = 0; ct < 4; ++ct) {
        const float b = bn1[ct * 16 + lc];
        #pragma unroll
        for (int rt = 0; rt < 2; ++rt)
            #pragma unroll
            for (int i = 0; i < 4; ++i) acc1[rt][ct][i] = b;
    }
    #pragma unroll
    for (int ks = 0; ks < 4; ++ks) {
        bf16x8 af[2];
        #pragma unroll
        for (int rt = 0; rt < 2; ++rt)
            af[rt] = *(const bf16x8*)&A[(rbase + rt * 16 + lc) * 136 + ks * 32 + q * 8];
        #pragma unroll
        for (int ct = 0; ct < 4; ++ct) {
            const bf16x8 bf = *(const bf16x8*)&Wtn1[(ct * 16 + lc) * 128 + ks * 32 + q * 8];
            #pragma unroll
            for (int rt = 0; rt < 2; ++rt)
                acc1[rt][ct] = MFMA16(af[rt], bf, acc1[rt][ct]);
        }
    }
    __syncthreads();

    #pragma unroll
    for (int rt = 0; rt < 2; ++rt)
        #pragma unroll
        for (int ct = 0; ct < 4; ++ct)
            #pragma unroll
            for (int i = 0; i < 4; ++i) {
                const int row = rbase + rt * 16 + q * 4 + i;
                A[row * 72 + ct * 16 + lc] = f2bf(fast_silu(acc1[rt][ct][i]));
            }
    __syncthreads();

    f32x4 acc2[2][4];
    #pragma unroll
    for (int ct = 0; ct < 4; ++ct) {
        const float b = bn2[ct * 16 + lc];
        #pragma unroll
        for (int rt = 0; rt < 2; ++rt)
            #pragma unroll
            for (int i = 0; i < 4; ++i) acc2[rt][ct][i] = b;
    }
    #pragma unroll
    for (int ks = 0; ks < 2; ++ks) {
        bf16x8 af[2];
        #pragma unroll
        for (int rt = 0; rt < 2; ++rt)
            af[rt] = *(const bf16x8*)&A[(rbase + rt * 16 + lc) * 72 + ks * 32 + q * 8];
        #pragma unroll
        for (int ct = 0; ct < 4; ++ct) {
            const bf16x8 bf = *(const bf16x8*)&Wtn2[(ct * 16 + lc) * 64 + ks * 32 + q * 8];
            #pragma unroll
            for (int rt = 0; rt < 2; ++rt)
                acc2[rt][ct] = MFMA16(af[rt], bf, acc2[rt][ct]);
        }
    }

    #pragma unroll
    for (int rt = 0; rt < 2; ++rt)
        #pragma unroll
        for (int ct = 0; ct < 4; ++ct)
            #pragma unroll
            for (int i = 0; i < 4; ++i) {
                const int node = nbase + rbase + rt * 16 + q * 4 + i;
                if (node < N_NODES)
                    hout[(size_t)node * 64 + ct * 16 + lc] = acc2[rt][ct][i];
            }
}

// ============================================================================
// launch
// ============================================================================
extern "C" void kernel_launch(void* const* d_in, const int* in_sizes, int n_in,
                              void* d_out, int out_size, void* d_ws, size_t ws_size,
                              hipStream_t stream)
{
    const float* h     = (const float*)d_in[0];
    const float* coord = (const float*)d_in[1];
    const int*   eidx  = (const int*)d_in[2];
    const float* emask = (const float*)d_in[3];
    const float* We1   = (const float*)d_in[4];
    const float* be1   = (const float*)d_in[5];
    const float* We2   = (const float*)d_in[6];
    const float* be2   = (const float*)d_in[7];
    const float* Wn1   = (const float*)d_in[8];
    const float* bn1   = (const float*)d_in[9];
    const float* Wn2   = (const float*)d_in[10];
    const float* bn2   = (const float*)d_in[11];
    const float* Wc1   = (const float*)d_in[12];
    const float* bc1   = (const float*)d_in[13];
    const float* Wc2   = (const float*)d_in[14];

    float* hout = (float*)d_out;
    float* cout = hout + (size_t)N_NODES * 64;

    // ws layout: [agg | aggc] zeroed by prep; hist zeroed by tiny memset.
    char* p = (char*)d_ws;
    float* agg  = (float*)p;                      p += (size_t)N_NODES * 64 * 4; // 10.24 MB
    float* aggc = (float*)p;                      p += (size_t)N_NODES * 3 * 4;  // 0.48 MB
    int* hist   = (int*)p;                        p += (size_t)N_NODES * 4;      // 0.16 MB
    int* offs   = (int*)p;                        p += (size_t)N_NODES * 4;
    int* pos    = (int*)p;                        p += (size_t)N_NODES * 4;
    uint4* payload = (uint4*)p;                   p += (size_t)N_EDGES * 16;     // 20.48 MB
    unsigned short* h_bf = (unsigned short*)p;    p += (size_t)N_NODES * 64 * 2; // 5.12 MB
    float4* coord4 = (float4*)p;                  p += (size_t)N_NODES * 16;     // 0.64 MB
    unsigned short* Wt1  = (unsigned short*)p;    p += 8192 * 2;
    unsigned short* Wt2  = (unsigned short*)p;    p += 4096 * 2;
    unsigned short* Wtc1 = (unsigned short*)p;    p += 4096 * 2;
    unsigned short* Wtn1 = (unsigned short*)p;    p += 8192 * 2;
    unsigned short* Wtn2 = (unsigned short*)p;    p += 4096 * 2;

    hipMemsetAsync(hist, 0, (size_t)N_NODES * 4, stream);   // 160 KB only
    prep_hist_kernel<<<6637, 256, 0, stream>>>(h, coord, We1, We2, Wc1, Wn1, Wn2, eidx,
                                               agg, h_bf, coord4,
                                               Wt1, Wt2, Wtc1, Wtn1, Wtn2, hist);
    scan_kernel<<<1, 1024, 0, stream>>>(hist, offs, pos);
    scatter_kernel<<<N_EDGES / 1024, 256, 0, stream>>>(eidx, emask, coord4, pos, payload);
    egcl_edge_mfma<<<N_EDGES / 256, 256, 0, stream>>>(
        h_bf, payload, offs, hist,
        We1, be1, be2, bc1, Wc2, Wt1, Wt2, Wtc1, agg, aggc);
    egcl_node_coord<<<NODE_BLOCKS + (N_NODES * 3 + 255) / 256, 256, 0, stream>>>(
        h_bf, agg, bn1, bn2, Wtn1, Wtn2, coord, aggc, hist, hout, cout);
}

// Round 10
// 337.682 us; speedup vs baseline: 1.2658x; 1.1343x over previous
//
#include <hip/hip_runtime.h>
#include <stdint.h>

#define N_NODES 40000
#define N_EDGES 1280000
#define NODE_BLOCKS 313   // ceil(40000/128)

typedef __attribute__((ext_vector_type(8))) short bf16x8;   // 8 bf16 in 4 VGPRs
typedef __attribute__((ext_vector_type(4))) float f32x4;    // MFMA C/D
typedef __attribute__((ext_vector_type(2))) _Float16 f16x2;

#define MFMA16(a, b, c) __builtin_amdgcn_mfma_f32_16x16x32_bf16((a), (b), (c), 0, 0, 0)

#if defined(__has_builtin)
#if __has_builtin(__builtin_amdgcn_cvt_pk_bf16_f32)
#define HAS_CVT_PK_BF16 1
#endif
#endif

// ---------- helpers ----------
__device__ __forceinline__ float fast_silu(float x) {
    float e = __expf(-x);
    return x * __builtin_amdgcn_rcpf(1.0f + e);
}

__device__ __forceinline__ unsigned short f2bf(float x) {
    unsigned int u = __float_as_uint(x);
    u = (u + 0x7FFFu + ((u >> 16) & 1u)) >> 16;
    return (unsigned short)u;
}

__device__ __forceinline__ unsigned int pack_bf2(float a, float b) {
#ifdef HAS_CVT_PK_BF16
    typedef __attribute__((ext_vector_type(2))) __bf16 bf2_t;
    bf2_t r = __builtin_amdgcn_cvt_pk_bf16_f32(a, b);   // low = a, high = b, RNE
    return __builtin_bit_cast(unsigned int, r);
#else
    unsigned int ua = __float_as_uint(a);
    unsigned int ub = __float_as_uint(b);
    ua = (ua + 0x7FFFu + ((ua >> 16) & 1u)) >> 16;
    ub = (ub + 0x7FFFu + ((ub >> 16) & 1u)) & 0xFFFF0000u;
    return (ua & 0xFFFFu) | ub;
#endif
}

__device__ __forceinline__ float bf16_to_f(unsigned short s) {
    return __uint_as_float(((unsigned int)s) << 16);
}

__device__ __forceinline__ unsigned int pk_f16(float a, float b) {
    f16x2 v; v.x = (_Float16)a; v.y = (_Float16)b;
    return __builtin_bit_cast(unsigned int, v);
}
__device__ __forceinline__ float f16_lo(unsigned int u) {
    f16x2 v = __builtin_bit_cast(f16x2, u); return (float)v.x;
}
__device__ __forceinline__ float f16_hi(unsigned int u) {
    f16x2 v = __builtin_bit_cast(f16x2, u); return (float)v.y;
}

// ============================================================================
// k1: hist + rank (the atomic's return value IS the in-row rank),
//     plus coord4 build and weight packing (independent block ranges).
//   [0, 1250)     : hist/rank over edges
//   [1250, 1407)  : coord -> float4
//   [1407, 1519)  : weight transpose+pack
// ============================================================================
__global__ void hist_rank_kernel(const int* __restrict__ eidx, const float* __restrict__ coord,
                                 const float* __restrict__ We1, const float* __restrict__ We2,
                                 const float* __restrict__ Wc1, const float* __restrict__ Wn1,
                                 const float* __restrict__ Wn2,
                                 int* __restrict__ hist, int* __restrict__ rank,
                                 float4* __restrict__ coord4,
                                 unsigned short* __restrict__ Wt1, unsigned short* __restrict__ Wt2,
                                 unsigned short* __restrict__ Wtc1, unsigned short* __restrict__ Wtn1,
                                 unsigned short* __restrict__ Wtn2)
{
    const int b = blockIdx.x;
    if (b < 1250) {
        const int i = (b * 256 + threadIdx.x) * 4;
        const int4 r = *(const int4*)(eidx + i);
        int4 k;
        k.x = atomicAdd(&hist[r.x], 1);
        k.y = atomicAdd(&hist[r.y], 1);
        k.z = atomicAdd(&hist[r.z], 1);
        k.w = atomicAdd(&hist[r.w], 1);
        *(int4*)(rank + i) = k;
    } else if (b < 1407) {
        const int n = (b - 1250) * 256 + threadIdx.x;
        if (n < N_NODES)
            coord4[n] = make_float4(coord[n * 3 + 0], coord[n * 3 + 1], coord[n * 3 + 2], 0.f);
    } else {
        const int t = (b - 1407) * 256 + threadIdx.x;
        if (t < 8192)       { Wt1[t]  = f2bf(We1[(t & 127) * 64 + (t >> 7)]); }
        else if (t < 12288) { int u = t - 8192;  Wt2[u]  = f2bf(We2[(u & 63) * 64 + (u >> 6)]); }
        else if (t < 16384) { int u = t - 12288; Wtc1[u] = f2bf(Wc1[(u & 63) * 64 + (u >> 6)]); }
        else if (t < 24576) { int u = t - 16384; Wtn1[u] = f2bf(Wn1[(u & 127) * 64 + (u >> 7)]); }
        else if (t < 28672) { int u = t - 24576; Wtn2[u] = f2bf(Wn2[(u & 63) * 64 + (u >> 6)]); }
    }
}

// ============================================================================
// k2: single-block scan (offs only)
// ============================================================================
__global__ __launch_bounds__(1024) void scan_kernel(const int* __restrict__ hist,
                                                    int* __restrict__ offs) {
    __shared__ int wtot[16];
    __shared__ int carry_s;
    const int t = threadIdx.x;
    const int wave = t >> 6, lane = t & 63;
    if (t == 0) carry_s = 0;
    __syncthreads();
    for (int base = 0; base < N_NODES; base += 8192) {
        const int idx = base + t * 8;
        int v[8];
        if (idx + 8 <= N_NODES) {
            const int4 a = *(const int4*)(hist + idx);
            const int4 b = *(const int4*)(hist + idx + 4);
            v[0] = a.x; v[1] = a.y; v[2] = a.z; v[3] = a.w;
            v[4] = b.x; v[5] = b.y; v[6] = b.z; v[7] = b.w;
        } else {
            #pragma unroll
            for (int j = 0; j < 8; ++j) v[j] = (idx + j < N_NODES) ? hist[idx + j] : 0;
        }
        int s = 0;
        #pragma unroll
        for (int j = 0; j < 8; ++j) s += v[j];
        int S = s;
        #pragma unroll
        for (int d = 1; d < 64; d <<= 1) {
            const int u = __shfl_up(S, d, 64);
            if (lane >= d) S += u;
        }
        if (lane == 63) wtot[wave] = S;
        __syncthreads();
        if (wave == 0 && lane < 16) {
            int w = wtot[lane];
            #pragma unroll
            for (int d = 1; d < 16; d <<= 1) {
                const int u = __shfl_up(w, d, 64);
                if (lane >= d) w += u;
            }
            wtot[lane] = w;
        }
        __syncthreads();
        const int wb = (wave == 0) ? 0 : wtot[wave - 1];
        int run = carry_s + wb + (S - s);
        #pragma unroll
        for (int j = 0; j < 8; ++j) {
            if (idx + j < N_NODES) offs[idx + j] = run;
            run += v[j];
        }
        __syncthreads();
        if (t == 0) carry_s += wtot[15];
        __syncthreads();
    }
}

// ============================================================================
// k3: scatter (NO atomics: slot = offs[r] + rank[e]) + h pack + agg zero
//   [0, 1250)     : scatter 16B payloads
//   [1250, 3750)  : pack h -> bf16
//   [3750, 6368)  : zero agg+aggc
// ============================================================================
__global__ void scatter_prep_kernel(const int* __restrict__ eidx, const float* __restrict__ emask,
                                    const int* __restrict__ rank, const int* __restrict__ offs,
                                    const float4* __restrict__ coord4,
                                    uint4* __restrict__ payload,
                                    const float* __restrict__ h,
                                    unsigned short* __restrict__ h_bf,
                                    float* __restrict__ aggz)
{
    const int b = blockIdx.x;
    if (b < 1250) {
        const int i = (b * 256 + threadIdx.x) * 4;
        const int4 r = *(const int4*)(eidx + i);
        const int4 c = *(const int4*)(eidx + N_EDGES + i);
        const float4 mk = *(const float4*)(emask + i);
        const int4 k = *(const int4*)(rank + i);
        #pragma unroll
        for (int j = 0; j < 4; ++j) {
            const int rj = (&r.x)[j], cj = (&c.x)[j];
            const float4 cr = coord4[rj];
            const float4 cc = coord4[cj];
            const float d0 = cr.x - cc.x, d1 = cr.y - cc.y, d2 = cr.z - cc.z;
            const float rad = d0 * d0 + d1 * d1 + d2 * d2;
            const int slot = offs[rj] + (&k.x)[j];
            payload[slot] = make_uint4((unsigned)rj | ((unsigned)cj << 16),
                                       pk_f16(d0, d1), pk_f16(d2, (&mk.x)[j]),
                                       __float_as_uint(rad));
        }
    } else if (b < 3750) {
        const int i = ((b - 1250) * 256 + threadIdx.x) * 4;   // exactly covers 2,560,000
        const float4 v = *(const float4*)(h + i);
        *(uint2*)(h_bf + i) = make_uint2(pack_bf2(v.x, v.y), pack_bf2(v.z, v.w));
    } else {
        const int i = ((b - 3750) * 256 + threadIdx.x) * 4;
        if (i < N_NODES * 67)
            *(float4*)(aggz + i) = make_float4(0.f, 0.f, 0.f, 0.f);
    }
}

// ============================================================================
// k4: edge kernel — byte-identical to R9 (proven 149 us)
// ============================================================================
__global__ __launch_bounds__(256, 4) void egcl_edge_mfma(
    const unsigned short* __restrict__ h_bf,
    const uint4* __restrict__ payload,
    const int* __restrict__ offs_g, const int* __restrict__ hist_g,
    const float* __restrict__ We1, const float* __restrict__ be1,
    const float* __restrict__ be2, const float* __restrict__ bc1,
    const float* __restrict__ Wc2,
    const unsigned short* __restrict__ Wt1, const unsigned short* __restrict__ Wt2,
    const unsigned short* __restrict__ Wtc1,
    float* __restrict__ agg, float* __restrict__ aggc)
{
    __shared__ __align__(16) unsigned short A[256 * 72];
    __shared__ float dif_s[768];
    __shared__ float cval_s[256];

    const int t = threadIdx.x;
    const int w = t >> 6, L = t & 63;
    const int q = L >> 4, lc = L & 15;
    const int ebase = blockIdx.x * 256;
    const int rbase = w * 64;

    // ---- meta: ONE coalesced 16B payload read; no dependent random loads ----
    int my_r, my_c;
    float my_rad, my_msk;
    {
        const uint4 pl = payload[ebase + t];
        my_r = (int)(pl.x & 0xFFFFu);
        my_c = (int)(pl.x >> 16);
        const float d0 = f16_lo(pl.y);
        const float d1 = f16_hi(pl.y);
        const float d2 = f16_lo(pl.z);
        my_msk = f16_hi(pl.z);
        my_rad = __uint_as_float(pl.w);
        dif_s[t * 3 + 0] = d0; dif_s[t * 3 + 1] = d1; dif_s[t * 3 + 2] = d2;
        if (t == 0)   *(int*)&A[64] = my_r;   // n0 in row-0 padding
        if (t == 255) *(int*)&A[66] = my_r;   // n1
    }

    // ---- stage h_bf[row] (k = 0..63), wave-private rows via shfl ----
    #pragma unroll
    for (int it = 0; it < 8; ++it) {
        const int rloc = it * 8 + (L >> 3);
        const int part = L & 7;
        const int ridx = __shfl(my_r, rloc, 64);
        const bf16x8 v = *(const bf16x8*)(h_bf + (size_t)ridx * 64 + part * 8);
        *(bf16x8*)&A[(rbase + rloc) * 72 + part * 8] = v;
    }

    // per-et rad / mask via shfl (slot et*16+lc is in this wave)
    float rad_et[4], mk_et[4];
    #pragma unroll
    for (int et = 0; et < 4; ++et) {
        rad_et[et] = __shfl(my_rad, et * 16 + lc, 64);
        mk_et[et]  = __shfl(my_msk, et * 16 + lc, 64);
    }

    // ---- layer1 init ----
    f32x4 acc[4][4];   // [ot][et]
    #pragma unroll
    for (int ot = 0; ot < 4; ++ot) {
        const float4 bv = *(const float4*)(be1 + ot * 16 + q * 4);
        const float4 wv = *(const float4*)(We1 + 128 * 64 + ot * 16 + q * 4);
        #pragma unroll
        for (int et = 0; et < 4; ++et) {
            const float rad = rad_et[et];
            acc[ot][et][0] = fmaf(rad, wv.x, bv.x);
            acc[ot][et][1] = fmaf(rad, wv.y, bv.y);
            acc[ot][et][2] = fmaf(rad, wv.z, bv.z);
            acc[ot][et][3] = fmaf(rad, wv.w, bv.w);
        }
    }

    // ---- layer1 MFMA, k = 0..63 (h[row]) ----
    #pragma unroll
    for (int ks = 0; ks < 2; ++ks) {
        bf16x8 bfr[4];
        #pragma unroll
        for (int et = 0; et < 4; ++et)
            bfr[et] = *(const bf16x8*)&A[(rbase + et * 16 + lc) * 72 + ks * 32 + q * 8];
        #pragma unroll
        for (int ot = 0; ot < 4; ++ot) {
            const bf16x8 af = *(const bf16x8*)&Wt1[(ot * 16 + lc) * 128 + ks * 32 + q * 8];
            #pragma unroll
            for (int et = 0; et < 4; ++et)
                acc[ot][et] = MFMA16(af, bfr[et], acc[ot][et]);
        }
    }

    // ---- restage h_bf[col] ----
    #pragma unroll
    for (int it = 0; it < 8; ++it) {
        const int rloc = it * 8 + (L >> 3);
        const int part = L & 7;
        const int cidx = __shfl(my_c, rloc, 64);
        const bf16x8 v = *(const bf16x8*)(h_bf + (size_t)cidx * 64 + part * 8);
        *(bf16x8*)&A[(rbase + rloc) * 72 + part * 8] = v;
    }

    // ---- layer1 MFMA, k = 64..127 (h[col]) ----
    #pragma unroll
    for (int ks = 0; ks < 2; ++ks) {
        bf16x8 bfr[4];
        #pragma unroll
        for (int et = 0; et < 4; ++et)
            bfr[et] = *(const bf16x8*)&A[(rbase + et * 16 + lc) * 72 + ks * 32 + q * 8];
        #pragma unroll
        for (int ot = 0; ot < 4; ++ot) {
            const bf16x8 af = *(const bf16x8*)&Wt1[(ot * 16 + lc) * 128 + 64 + ks * 32 + q * 8];
            #pragma unroll
            for (int et = 0; et < 4; ++et)
                acc[ot][et] = MFMA16(af, bfr[et], acc[ot][et]);
        }
    }

    // ---- m1 = silu -> A ----
    #pragma unroll
    for (int et = 0; et < 4; ++et) {
        const int row = rbase + et * 16 + lc;
        #pragma unroll
        for (int ot = 0; ot < 4; ++ot) {
            uint2 p;
            p.x = pack_bf2(fast_silu(acc[ot][et][0]), fast_silu(acc[ot][et][1]));
            p.y = pack_bf2(fast_silu(acc[ot][et][2]), fast_silu(acc[ot][et][3]));
            *(uint2*)&A[row * 72 + ot * 16 + q * 4] = p;
        }
    }

    // ---- layer2 ----
    f32x4 acc2[4][4];
    #pragma unroll
    for (int ot = 0; ot < 4; ++ot) {
        const float4 bv = *(const float4*)(be2 + ot * 16 + q * 4);
        #pragma unroll
        for (int et = 0; et < 4; ++et) {
            acc2[ot][et][0] = bv.x; acc2[ot][et][1] = bv.y;
            acc2[ot][et][2] = bv.z; acc2[ot][et][3] = bv.w;
        }
    }
    #pragma unroll
    for (int ks = 0; ks < 2; ++ks) {
        bf16x8 bfr[4];
        #pragma unroll
        for (int et = 0; et < 4; ++et)
            bfr[et] = *(const bf16x8*)&A[(rbase + et * 16 + lc) * 72 + ks * 32 + q * 8];
        #pragma unroll
        for (int ot = 0; ot < 4; ++ot) {
            const bf16x8 af = *(const bf16x8*)&Wt2[(ot * 16 + lc) * 64 + ks * 32 + q * 8];
            #pragma unroll
            for (int et = 0; et < 4; ++et)
                acc2[ot][et] = MFMA16(af, bfr[et], acc2[ot][et]);
        }
    }

    // ---- m = silu * mask -> A ----
    #pragma unroll
    for (int et = 0; et < 4; ++et) {
        const int row = rbase + et * 16 + lc;
        const float mk = mk_et[et];
        #pragma unroll
        for (int ot = 0; ot < 4; ++ot) {
            uint2 p;
            p.x = pack_bf2(fast_silu(acc2[ot][et][0]) * mk, fast_silu(acc2[ot][et][1]) * mk);
            p.y = pack_bf2(fast_silu(acc2[ot][et][2]) * mk, fast_silu(acc2[ot][et][3]) * mk);
            *(uint2*)&A[row * 72 + ot * 16 + q * 4] = p;
        }
    }

    // ---- coord mlp ----
    f32x4 acc3[4][4];
    #pragma unroll
    for (int ot = 0; ot < 4; ++ot) {
        const float4 bv = *(const float4*)(bc1 + ot * 16 + q * 4);
        #pragma unroll
        for (int et = 0; et < 4; ++et) {
            acc3[ot][et][0] = bv.x; acc3[ot][et][1] = bv.y;
            acc3[ot][et][2] = bv.z; acc3[ot][et][3] = bv.w;
        }
    }
    #pragma unroll
    for (int ks = 0; ks < 2; ++ks) {
        bf16x8 bfr[4];
        #pragma unroll
        for (int et = 0; et < 4; ++et)
            bfr[et] = *(const bf16x8*)&A[(rbase + et * 16 + lc) * 72 + ks * 32 + q * 8];
        #pragma unroll
        for (int ot = 0; ot < 4; ++ot) {
            const bf16x8 af = *(const bf16x8*)&Wtc1[(ot * 16 + lc) * 64 + ks * 32 + q * 8];
            #pragma unroll
            for (int et = 0; et < 4; ++et)
                acc3[ot][et] = MFMA16(af, bfr[et], acc3[ot][et]);
        }
    }
    {
        float4 wv[4];
        #pragma unroll
        for (int ot = 0; ot < 4; ++ot) wv[ot] = *(const float4*)(Wc2 + ot * 16 + q * 4);
        #pragma unroll
        for (int et = 0; et < 4; ++et) {
            float s = 0.0f;
            #pragma unroll
            for (int ot = 0; ot < 4; ++ot) {
                s = fmaf(fast_silu(acc3[ot][et][0]), wv[ot].x, s);
                s = fmaf(fast_silu(acc3[ot][et][1]), wv[ot].y, s);
                s = fmaf(fast_silu(acc3[ot][et][2]), wv[ot].z, s);
                s = fmaf(fast_silu(acc3[ot][et][3]), wv[ot].w, s);
            }
            s += __shfl_xor(s, 16, 64);
            s += __shfl_xor(s, 32, 64);
            if (q == 0)
                cval_s[rbase + et * 16 + lc] = s * mk_et[et];
        }
    }

    __syncthreads();   // whole block's m / cval / dif now valid

    // ---- fused segmented aggregation ----
    {
        const int n0 = *(const int*)&A[64];
        const int n1 = *(const int*)&A[66];
        for (int n = n0 + w; n <= n1; n += 4) {
            const int os = offs_g[n];
            const int dg = hist_g[n];
            const int s0 = max(os - ebase, 0);
            const int s1 = min(os + dg - ebase, 256);
            float s = 0.0f, t3 = 0.0f;
            const bool c3 = (L < 3);
            int slot = s0;
            for (; slot + 4 <= s1; slot += 4) {
                const float a0 = bf16_to_f(A[(slot + 0) * 72 + L]);
                const float a1 = bf16_to_f(A[(slot + 1) * 72 + L]);
                const float a2 = bf16_to_f(A[(slot + 2) * 72 + L]);
                const float a3 = bf16_to_f(A[(slot + 3) * 72 + L]);
                s += (a0 + a1) + (a2 + a3);
                if (c3) {
                    t3 = fmaf(dif_s[(slot + 0) * 3 + L], cval_s[slot + 0], t3);
                    t3 = fmaf(dif_s[(slot + 1) * 3 + L], cval_s[slot + 1], t3);
                    t3 = fmaf(dif_s[(slot + 2) * 3 + L], cval_s[slot + 2], t3);
                    t3 = fmaf(dif_s[(slot + 3) * 3 + L], cval_s[slot + 3], t3);
                }
            }
            for (; slot < s1; ++slot) {
                s += bf16_to_f(A[slot * 72 + L]);
                if (c3) t3 = fmaf(dif_s[slot * 3 + L], cval_s[slot], t3);
            }
            const bool interior = (os >= ebase) && (os + dg <= ebase + 256);
            if (interior) {
                agg[(size_t)n * 64 + L] = s;
                if (c3) aggc[n * 3 + L] = t3;
            } else {
                atomicAdd(&agg[(size_t)n * 64 + L], s);
                if (c3) atomicAdd(&aggc[n * 3 + L], t3);
            }
        }
    }
}

// ============================================================================
// k5: node MLP + coord output fused — identical to R9
// ============================================================================
__global__ __launch_bounds__(256, 4) void egcl_node_coord(
    const unsigned short* __restrict__ h_bf, const float* __restrict__ agg,
    const float* __restrict__ bn1, const float* __restrict__ bn2,
    const unsigned short* __restrict__ Wtn1, const unsigned short* __restrict__ Wtn2,
    const float* __restrict__ coord, const float* __restrict__ aggc,
    const int* __restrict__ hist,
    float* __restrict__ hout, float* __restrict__ cout)
{
    if (blockIdx.x >= NODE_BLOCKS) {
        const int i = (blockIdx.x - NODE_BLOCKS) * 256 + threadIdx.x;
        if (i < N_NODES * 3) {
            const int node = i / 3;
            const float c = fmaxf((float)hist[node], 1.0f);
            cout[i] = coord[i] + aggc[i] * __builtin_amdgcn_rcpf(c);
        }
        return;
    }

    __shared__ __align__(16) unsigned short A[128 * 136];
    const int t = threadIdx.x;
    const int wave = t >> 6, L = t & 63;
    const int q = L >> 4, lc = L & 15;
    const int nbase = blockIdx.x * 128;
    const int rbase = wave * 32;

    #pragma unroll 4
    for (int it = 0; it < 16; ++it) {
        const int idx = it * 256 + t;
        const int ln = idx >> 5, part = idx & 31;
        const int node = nbase + ln;
        uint2 u = make_uint2(0u, 0u);
        if (node < N_NODES) {
            if (part < 16) {
                u = *(const uint2*)(h_bf + (size_t)node * 64 + part * 4);
            } else {
                const float4 v = *(const float4*)(agg + (size_t)node * 64 + (part - 16) * 4);
                u = make_uint2(pack_bf2(v.x, v.y), pack_bf2(v.z, v.w));
            }
        }
        *(uint2*)&A[ln * 136 + part * 4] = u;
    }
    __syncthreads();

    f32x4 acc1[2][4];
    #pragma unroll
    for (int ct = 0; ct < 4; ++ct) {
        const float b = bn1[ct * 16 + lc];
        #pragma unroll
        for (int rt = 0; rt < 2; ++rt)
            #pragma unroll
            for (int i = 0; i < 4; ++i) acc1[rt][ct][i] = b;
    }
    #pragma unroll
    for (int ks = 0; ks < 4; ++ks) {
        bf16x8 af[2];
        #pragma unroll
        for (int rt = 0; rt < 2; ++rt)
            af[rt] = *(const bf16x8*)&A[(rbase + rt * 16 + lc) * 136 + ks * 32 + q * 8];
        #pragma unroll
        for (int ct = 0; ct < 4; ++ct) {
            const bf16x8 bf = *(const bf16x8*)&Wtn1[(ct * 16 + lc) * 128 + ks * 32 + q * 8];
            #pragma unroll
            for (int rt = 0; rt < 2; ++rt)
                acc1[rt][ct] = MFMA16(af[rt], bf, acc1[rt][ct]);
        }
    }
    __syncthreads();

    #pragma unroll
    for (int rt = 0; rt < 2; ++rt)
        #pragma unroll
        for (int ct = 0; ct < 4; ++ct)
            #pragma unroll
            for (int i = 0; i < 4; ++i) {
                const int row = rbase + rt * 16 + q * 4 + i;
                A[row * 72 + ct * 16 + lc] = f2bf(fast_silu(acc1[rt][ct][i]));
            }
    __syncthreads();

    f32x4 acc2[2][4];
    #pragma unroll
    for (int ct = 0; ct < 4; ++ct) {
        const float b = bn2[ct * 16 + lc];
        #pragma unroll
        for (int rt = 0; rt < 2; ++rt)
            #pragma unroll
            for (int i = 0; i < 4; ++i) acc2[rt][ct][i] = b;
    }
    #pragma unroll
    for (int ks = 0; ks < 2; ++ks) {
        bf16x8 af[2];
        #pragma unroll
        for (int rt = 0; rt < 2; ++rt)
            af[rt] = *(const bf16x8*)&A[(rbase + rt * 16 + lc) * 72 + ks * 32 + q * 8];
        #pragma unroll
        for (int ct = 0; ct < 4; ++ct) {
            const bf16x8 bf = *(const bf16x8*)&Wtn2[(ct * 16 + lc) * 64 + ks * 32 + q * 8];
            #pragma unroll
            for (int rt = 0; rt < 2; ++rt)
                acc2[rt][ct] = MFMA16(af[rt], bf, acc2[rt][ct]);
        }
    }

    #pragma unroll
    for (int rt = 0; rt < 2; ++rt)
        #pragma unroll
        for (int ct = 0; ct < 4; ++ct)
            #pragma unroll
            for (int i = 0; i < 4; ++i) {
                const int node = nbase + rbase + rt * 16 + q * 4 + i;
                if (node < N_NODES)
                    hout[(size_t)node * 64 + ct * 16 + lc] = acc2[rt][ct][i];
            }
}

// ============================================================================
// launch
// ============================================================================
extern "C" void kernel_launch(void* const* d_in, const int* in_sizes, int n_in,
                              void* d_out, int out_size, void* d_ws, size_t ws_size,
                              hipStream_t stream)
{
    const float* h     = (const float*)d_in[0];
    const float* coord = (const float*)d_in[1];
    const int*   eidx  = (const int*)d_in[2];
    const float* emask = (const float*)d_in[3];
    const float* We1   = (const float*)d_in[4];
    const float* be1   = (const float*)d_in[5];
    const float* We2   = (const float*)d_in[6];
    const float* be2   = (const float*)d_in[7];
    const float* Wn1   = (const float*)d_in[8];
    const float* bn1   = (const float*)d_in[9];
    const float* Wn2   = (const float*)d_in[10];
    const float* bn2   = (const float*)d_in[11];
    const float* Wc1   = (const float*)d_in[12];
    const float* bc1   = (const float*)d_in[13];
    const float* Wc2   = (const float*)d_in[14];

    float* hout = (float*)d_out;
    float* cout = hout + (size_t)N_NODES * 64;

    // ws layout
    char* p = (char*)d_ws;
    float* agg  = (float*)p;                      p += (size_t)N_NODES * 64 * 4; // 10.24 MB
    float* aggc = (float*)p;                      p += (size_t)N_NODES * 3 * 4;  // 0.48 MB
    int* hist   = (int*)p;                        p += (size_t)N_NODES * 4;      // 0.16 MB
    int* offs   = (int*)p;                        p += (size_t)N_NODES * 4;
    int* rank   = (int*)p;                        p += (size_t)N_EDGES * 4;      // 5.12 MB
    uint4* payload = (uint4*)p;                   p += (size_t)N_EDGES * 16;     // 20.48 MB
    unsigned short* h_bf = (unsigned short*)p;    p += (size_t)N_NODES * 64 * 2; // 5.12 MB
    float4* coord4 = (float4*)p;                  p += (size_t)N_NODES * 16;     // 0.64 MB
    unsigned short* Wt1  = (unsigned short*)p;    p += 8192 * 2;
    unsigned short* Wt2  = (unsigned short*)p;    p += 4096 * 2;
    unsigned short* Wtc1 = (unsigned short*)p;    p += 4096 * 2;
    unsigned short* Wtn1 = (unsigned short*)p;    p += 8192 * 2;
    unsigned short* Wtn2 = (unsigned short*)p;    p += 4096 * 2;

    hipMemsetAsync(hist, 0, (size_t)N_NODES * 4, stream);   // 160 KB only
    hist_rank_kernel<<<1519, 256, 0, stream>>>(eidx, coord, We1, We2, Wc1, Wn1, Wn2,
                                               hist, rank, coord4,
                                               Wt1, Wt2, Wtc1, Wtn1, Wtn2);
    scan_kernel<<<1, 1024, 0, stream>>>(hist, offs);
    scatter_prep_kernel<<<6368, 256, 0, stream>>>(eidx, emask, rank, offs, coord4,
                                                  payload, h, h_bf, agg);
    egcl_edge_mfma<<<N_EDGES / 256, 256, 0, stream>>>(
        h_bf, payload, offs, hist,
        We1, be1, be2, bc1, Wc2, Wt1, Wt2, Wtc1, agg, aggc);
    egcl_node_coord<<<NODE_BLOCKS + (N_NODES * 3 + 255) / 256, 256, 0, stream>>>(
        h_bf, agg, bn1, bn2, Wtn1, Wtn2, coord, aggc, hist, hout, cout);
}